// Round 1
// baseline (506.662 us; speedup 1.0000x reference)
//
#include <hip/hip_runtime.h>

typedef unsigned short u16;
typedef __attribute__((ext_vector_type(8))) short short8;
typedef __attribute__((ext_vector_type(4))) float floatx4;

// ---------- helpers ----------
__device__ inline u16 f2bf(float x) {
  union { float f; unsigned u; } v; v.f = x;
  unsigned r = v.u + 0x7FFFu + ((v.u >> 16) & 1u);   // RNE
  return (u16)(r >> 16);
}
__device__ inline void cp16(u16* dst, const u16* src) {
  *reinterpret_cast<float4*>(dst) = *reinterpret_cast<const float4*>(src);
}
__device__ inline short8 ld8(const u16* p) {
  return *reinterpret_cast<const short8*>(p);
}

// ---------- weight cast fp32 -> bf16 ----------
__global__ __launch_bounds__(256) void cast_bf16(const float* __restrict__ src,
                                                 u16* __restrict__ dst) {
  int i = blockIdx.x * 256 + threadIdx.x;
  float4 v = reinterpret_cast<const float4*>(src)[i];
  union { u16 u[4]; float2 f; } w;
  w.u[0] = f2bf(v.x); w.u[1] = f2bf(v.y); w.u[2] = f2bf(v.z); w.u[3] = f2bf(v.w);
  reinterpret_cast<float2*>(dst)[i] = w.f;
}

// ---------- GroupNorm 1: x (B,C,T) fp32 -> xn (B,T,C) bf16 ----------
// block = (b,g), group = 16 channels x 2048 t = 32768 contiguous floats
__global__ __launch_bounds__(256) void gn_ct(const float* __restrict__ x,
                                             const float* __restrict__ gamma,
                                             const float* __restrict__ beta,
                                             u16* __restrict__ xn) {
  int b = blockIdx.x >> 5, g = blockIdx.x & 31;
  const float* base = x + ((long)b * 512 + g * 16) * 2048;
  float s = 0.f, ss = 0.f;
  for (int i = threadIdx.x; i < 8192; i += 256) {
    float4 v = reinterpret_cast<const float4*>(base)[i];
    s  += v.x + v.y + v.z + v.w;
    ss += v.x * v.x + v.y * v.y + v.z * v.z + v.w * v.w;
  }
  #pragma unroll
  for (int d = 1; d < 64; d <<= 1) { s += __shfl_xor(s, d); ss += __shfl_xor(ss, d); }
  __shared__ float red[8];
  int wave = threadIdx.x >> 6, lane = threadIdx.x & 63;
  if (lane == 0) { red[wave] = s; red[wave + 4] = ss; }
  __syncthreads();
  s  = red[0] + red[1] + red[2] + red[3];
  ss = red[4] + red[5] + red[6] + red[7];
  float mean = s * (1.f / 32768.f);
  float var  = ss * (1.f / 32768.f) - mean * mean;
  float rstd = rsqrtf(var + 1e-5f);
  float ga[16], be[16];
  #pragma unroll
  for (int c = 0; c < 16; c++) {
    float gm = gamma[g * 16 + c];
    ga[c] = gm * rstd;
    be[c] = beta[g * 16 + c] - mean * rstd * gm;
  }
  u16* ob = xn + (long)b * 2048 * 512 + g * 16;
  for (int t = threadIdx.x; t < 2048; t += 256) {
    union { u16 u[8]; float4 f; } w0, w1;
    #pragma unroll
    for (int c = 0; c < 8; c++)  w0.u[c]     = f2bf(base[c * 2048 + t] * ga[c] + be[c]);
    #pragma unroll
    for (int c = 8; c < 16; c++) w1.u[c - 8] = f2bf(base[c * 2048 + t] * ga[c] + be[c]);
    u16* dst = ob + (long)t * 512;
    *reinterpret_cast<float4*>(dst)     = w0.f;
    *reinterpret_cast<float4*>(dst + 8) = w1.f;
  }
}

// ---------- GroupNorm 2: a (B,T,C) fp32 -> hn (B,T,C) bf16 ----------
__global__ __launch_bounds__(256) void gn_tc(const float* __restrict__ a,
                                             const float* __restrict__ gamma,
                                             const float* __restrict__ beta,
                                             u16* __restrict__ hn) {
  int b = blockIdx.x >> 5, g = blockIdx.x & 31;
  const float* base = a + (long)b * 2048 * 512 + g * 16;
  float s = 0.f, ss = 0.f;
  for (int t = threadIdx.x; t < 2048; t += 256) {
    const float4* p = reinterpret_cast<const float4*>(base + (long)t * 512);
    #pragma unroll
    for (int j = 0; j < 4; j++) {
      float4 v = p[j];
      s  += v.x + v.y + v.z + v.w;
      ss += v.x * v.x + v.y * v.y + v.z * v.z + v.w * v.w;
    }
  }
  #pragma unroll
  for (int d = 1; d < 64; d <<= 1) { s += __shfl_xor(s, d); ss += __shfl_xor(ss, d); }
  __shared__ float red[8];
  int wave = threadIdx.x >> 6, lane = threadIdx.x & 63;
  if (lane == 0) { red[wave] = s; red[wave + 4] = ss; }
  __syncthreads();
  s  = red[0] + red[1] + red[2] + red[3];
  ss = red[4] + red[5] + red[6] + red[7];
  float mean = s * (1.f / 32768.f);
  float var  = ss * (1.f / 32768.f) - mean * mean;
  float rstd = rsqrtf(var + 1e-5f);
  float ga[16], be[16];
  #pragma unroll
  for (int c = 0; c < 16; c++) {
    float gm = gamma[g * 16 + c];
    ga[c] = gm * rstd;
    be[c] = beta[g * 16 + c] - mean * rstd * gm;
  }
  u16* ob = hn + (long)b * 2048 * 512 + g * 16;
  for (int t = threadIdx.x; t < 2048; t += 256) {
    const float* p = base + (long)t * 512;
    union { u16 u[8]; float4 f; } w0, w1;
    #pragma unroll
    for (int c = 0; c < 8; c++)  w0.u[c]     = f2bf(p[c] * ga[c] + be[c]);
    #pragma unroll
    for (int c = 8; c < 16; c++) w1.u[c - 8] = f2bf(p[c] * ga[c] + be[c]);
    u16* dst = ob + (long)t * 512;
    *reinterpret_cast<float4*>(dst)     = w0.f;
    *reinterpret_cast<float4*>(dst + 8) = w1.f;
  }
}

// ---------- unified TN GEMM: D[m][n] = sum_k A[m][k] * Bt[n][k] (+bias)(+resid) ----------
// A: M x K row-major bf16, Bt: N x K row-major bf16, both row stride == K.
// 128x128 block tile, BK=32, 4 waves in 2x2, each wave 4x4 MFMA 16x16x32 tiles.
#define LDK 40
template<int OUT_BF16, int BIAS_N, int RESID>
__global__ __launch_bounds__(256) void gemm_tn(
    const u16* __restrict__ A, long abst,
    const u16* __restrict__ Bt, long bbst,
    const float* __restrict__ bias,
    const float* __restrict__ resid, long rbst,
    void* __restrict__ outp, long obst, int K) {
  __shared__ __align__(16) u16 As[128 * LDK];
  __shared__ __align__(16) u16 Bs[128 * LDK];
  const int tid = threadIdx.x;
  const int m0 = blockIdx.y * 128, n0 = blockIdx.x * 128;
  const int N = gridDim.x * 128;
  const long bz = blockIdx.z;
  const u16* Ab = A + bz * abst + (long)m0 * K;
  const u16* Bb = Bt + bz * bbst + (long)n0 * K;
  const int sr = tid >> 2, so = (tid & 3) * 8;      // staging row/offset
  const int lane = tid & 63, wave = tid >> 6;
  const int wm = (wave & 1) * 64, wn = (wave >> 1) * 64;
  const int l15 = lane & 15, quad = lane >> 4;

  floatx4 acc[4][4];
  #pragma unroll
  for (int i = 0; i < 4; i++)
    #pragma unroll
    for (int j = 0; j < 4; j++) acc[i][j] = (floatx4){0.f, 0.f, 0.f, 0.f};

  for (int k0 = 0; k0 < K; k0 += 32) {
    __syncthreads();
    cp16(&As[sr * LDK + so],        Ab + (long)sr * K + k0 + so);
    cp16(&As[(sr + 64) * LDK + so], Ab + (long)(sr + 64) * K + k0 + so);
    cp16(&Bs[sr * LDK + so],        Bb + (long)sr * K + k0 + so);
    cp16(&Bs[(sr + 64) * LDK + so], Bb + (long)(sr + 64) * K + k0 + so);
    __syncthreads();
    short8 af[4], bf[4];
    #pragma unroll
    for (int i = 0; i < 4; i++) af[i] = ld8(&As[(wm + i * 16 + l15) * LDK + quad * 8]);
    #pragma unroll
    for (int i = 0; i < 4; i++) bf[i] = ld8(&Bs[(wn + i * 16 + l15) * LDK + quad * 8]);
    #pragma unroll
    for (int mi = 0; mi < 4; mi++)
      #pragma unroll
      for (int ni = 0; ni < 4; ni++)
        acc[mi][ni] = __builtin_amdgcn_mfma_f32_16x16x32_bf16(af[mi], bf[ni], acc[mi][ni], 0, 0, 0);
  }

  if (OUT_BF16) {
    u16* D = (u16*)outp + bz * obst;
    float bn[4];
    #pragma unroll
    for (int ni = 0; ni < 4; ni++) bn[ni] = BIAS_N ? bias[n0 + wn + ni * 16 + l15] : 0.f;
    #pragma unroll
    for (int mi = 0; mi < 4; mi++)
      #pragma unroll
      for (int ni = 0; ni < 4; ni++)
        #pragma unroll
        for (int r = 0; r < 4; r++) {
          int m = m0 + wm + mi * 16 + quad * 4 + r;
          int n = n0 + wn + ni * 16 + l15;
          D[(long)m * N + n] = f2bf(acc[mi][ni][r] + bn[ni]);
        }
  } else {
    float* D = (float*)outp + bz * obst;
    const float* R = RESID ? resid + bz * rbst : nullptr;
    #pragma unroll
    for (int mi = 0; mi < 4; mi++)
      #pragma unroll
      for (int r = 0; r < 4; r++) {
        int m = m0 + wm + mi * 16 + quad * 4 + r;
        float bm = BIAS_N ? 0.f : bias[m];
        #pragma unroll
        for (int ni = 0; ni < 4; ni++) {
          int n = n0 + wn + ni * 16 + l15;
          long idx = (long)m * N + n;
          float v = acc[mi][ni][r] + bm;
          if (RESID) v += R[idx];
          D[idx] = v;
        }
      }
  }
}

// ---------- flash attention ----------
// qkv: (B, T=2048, 1536) bf16; head h channels: q=h*192+[0,64), k=+64, v=+128
// block: 128 queries for one (b,h); 4 waves x 32 q-rows; KV tiles of 64.
#define LDC 72
__global__ __launch_bounds__(256) void attn(const u16* __restrict__ qkv,
                                            float* __restrict__ aout) {
  __shared__ __align__(16) u16 Ps[128 * LDC];  // Q tile at start, then P tiles
  __shared__ __align__(16) u16 Ks[64 * LDC];
  __shared__ __align__(16) u16 Vs[64 * LDC];
  const int tid = threadIdx.x, lane = tid & 63, wave = tid >> 6;
  const int l15 = lane & 15, quad = lane >> 4;
  const int b = blockIdx.y >> 3, h = blockIdx.y & 7;
  const int t0 = blockIdx.x * 128;
  const u16* base = qkv + (long)b * 2048 * 1536 + h * 192;

  // stage Q (128 x 64) as straight copy
  for (int i = tid; i < 1024; i += 256) {
    int rr = i >> 3, off = (i & 7) * 8;
    cp16(&Ps[rr * LDC + off], base + (long)(t0 + rr) * 1536 + off);
  }
  __syncthreads();
  short8 qf[2][2];
  #pragma unroll
  for (int mi = 0; mi < 2; mi++)
    #pragma unroll
    for (int ks = 0; ks < 2; ks++)
      qf[mi][ks] = ld8(&Ps[(wave * 32 + mi * 16 + l15) * LDC + ks * 32 + quad * 8]);

  float m_i[2][4], l_i[2][4];
  floatx4 accO[2][4];
  #pragma unroll
  for (int mi = 0; mi < 2; mi++)
    #pragma unroll
    for (int r = 0; r < 4; r++) { m_i[mi][r] = -1e30f; l_i[mi][r] = 0.f; }
  #pragma unroll
  for (int mi = 0; mi < 2; mi++)
    #pragma unroll
    for (int ci = 0; ci < 4; ci++) accO[mi][ci] = (floatx4){0.f, 0.f, 0.f, 0.f};

  const float SC = 0.125f * 1.44269504f;  // qk scale folded with log2(e)

  for (int s0 = 0; s0 < 2048; s0 += 64) {
    __syncthreads();
    // stage K (64 tk x 64 c), straight copy
    for (int i = tid; i < 512; i += 256) {
      int rr = i >> 3, off = (i & 7) * 8;
      cp16(&Ks[rr * LDC + off], base + (long)(s0 + rr) * 1536 + 64 + off);
    }
    // stage V transposed: Vs[c][tk]
    for (int i = tid; i < 512; i += 256) {
      int sv = i >> 3, cb = (i & 7) * 8;
      union { float4 f; u16 u[8]; } w;
      w.f = *reinterpret_cast<const float4*>(base + (long)(s0 + sv) * 1536 + 128 + cb);
      #pragma unroll
      for (int j = 0; j < 8; j++) Vs[(cb + j) * LDC + sv] = w.u[j];
    }
    __syncthreads();

    // S = Q K^T  (per wave: 32 q-rows x 64 tk)
    floatx4 sacc[2][4];
    #pragma unroll
    for (int mi = 0; mi < 2; mi++)
      #pragma unroll
      for (int ni = 0; ni < 4; ni++) sacc[mi][ni] = (floatx4){0.f, 0.f, 0.f, 0.f};
    #pragma unroll
    for (int ks = 0; ks < 2; ks++) {
      short8 kf[4];
      #pragma unroll
      for (int ni = 0; ni < 4; ni++)
        kf[ni] = ld8(&Ks[(ni * 16 + l15) * LDC + ks * 32 + quad * 8]);
      #pragma unroll
      for (int mi = 0; mi < 2; mi++)
        #pragma unroll
        for (int ni = 0; ni < 4; ni++)
          sacc[mi][ni] = __builtin_amdgcn_mfma_f32_16x16x32_bf16(qf[mi][ks], kf[ni], sacc[mi][ni], 0, 0, 0);
    }

    // online softmax (rows = quad*4+r within each 16-tile)
    float alpha[2][4];
    #pragma unroll
    for (int mi = 0; mi < 2; mi++)
      #pragma unroll
      for (int r = 0; r < 4; r++) {
        float mx = -1e30f;
        #pragma unroll
        for (int ni = 0; ni < 4; ni++) {
          sacc[mi][ni][r] *= SC;
          mx = fmaxf(mx, sacc[mi][ni][r]);
        }
        #pragma unroll
        for (int d = 1; d < 16; d <<= 1) mx = fmaxf(mx, __shfl_xor(mx, d));
        float mn = fmaxf(m_i[mi][r], mx);
        alpha[mi][r] = __builtin_amdgcn_exp2f(m_i[mi][r] - mn);
        m_i[mi][r] = mn;
        float rs = 0.f;
        #pragma unroll
        for (int ni = 0; ni < 4; ni++) {
          float p = __builtin_amdgcn_exp2f(sacc[mi][ni][r] - mn);
          sacc[mi][ni][r] = p;
          rs += p;
        }
        #pragma unroll
        for (int d = 1; d < 16; d <<= 1) rs += __shfl_xor(rs, d);
        l_i[mi][r] = l_i[mi][r] * alpha[mi][r] + rs;
      }
    #pragma unroll
    for (int mi = 0; mi < 2; mi++)
      #pragma unroll
      for (int ci = 0; ci < 4; ci++)
        #pragma unroll
        for (int r = 0; r < 4; r++) accO[mi][ci][r] *= alpha[mi][r];

    // P -> LDS (bf16), own wave's rows only
    #pragma unroll
    for (int mi = 0; mi < 2; mi++)
      #pragma unroll
      for (int ni = 0; ni < 4; ni++)
        #pragma unroll
        for (int r = 0; r < 4; r++)
          Ps[(wave * 32 + mi * 16 + quad * 4 + r) * LDC + ni * 16 + l15] = f2bf(sacc[mi][ni][r]);
    __syncthreads();

    // O += P V^T
    #pragma unroll
    for (int ks = 0; ks < 2; ks++) {
      short8 pf[2], vf[4];
      #pragma unroll
      for (int mi = 0; mi < 2; mi++)
        pf[mi] = ld8(&Ps[(wave * 32 + mi * 16 + l15) * LDC + ks * 32 + quad * 8]);
      #pragma unroll
      for (int ci = 0; ci < 4; ci++)
        vf[ci] = ld8(&Vs[(ci * 16 + l15) * LDC + ks * 32 + quad * 8]);
      #pragma unroll
      for (int mi = 0; mi < 2; mi++)
        #pragma unroll
        for (int ci = 0; ci < 4; ci++)
          accO[mi][ci] = __builtin_amdgcn_mfma_f32_16x16x32_bf16(pf[mi], vf[ci], accO[mi][ci], 0, 0, 0);
    }
  }

  // epilogue: normalize, write a (B,T,C) fp32
  float invl[2][4];
  #pragma unroll
  for (int mi = 0; mi < 2; mi++)
    #pragma unroll
    for (int r = 0; r < 4; r++) invl[mi][r] = 1.f / l_i[mi][r];
  float* ob = aout + ((long)b * 2048 + t0 + wave * 32) * 512 + h * 64;
  #pragma unroll
  for (int mi = 0; mi < 2; mi++)
    #pragma unroll
    for (int ci = 0; ci < 4; ci++)
      #pragma unroll
      for (int r = 0; r < 4; r++)
        ob[(long)(mi * 16 + quad * 4 + r) * 512 + ci * 16 + l15] = accO[mi][ci][r] * invl[mi][r];
}

// ---------- launch ----------
extern "C" void kernel_launch(void* const* d_in, const int* in_sizes, int n_in,
                              void* d_out, int out_size, void* d_ws, size_t ws_size,
                              hipStream_t stream) {
  const float* x   = (const float*)d_in[0];
  const float* g1  = (const float*)d_in[1];
  const float* be1 = (const float*)d_in[2];
  const float* wq  = (const float*)d_in[3];
  const float* bq  = (const float*)d_in[4];
  const float* g2  = (const float*)d_in[5];
  const float* be2 = (const float*)d_in[6];
  const float* wp  = (const float*)d_in[7];
  const float* bp  = (const float*)d_in[8];

  char* ws = (char*)d_ws;
  // region 0 (33.5MB): xn (bf16, 16.8MB) early, reused as a (fp32) after gemm1
  u16*   xn  = (u16*)ws;
  float* a   = (float*)ws;
  u16*   qkvb = (u16*)(ws + 33554432);          // 50.3 MB
  u16*   hn  = (u16*)(ws + 83886080);           // 16.8 MB
  u16*   wqb = (u16*)(ws + 100663296);          // 1.6 MB
  u16*   wpb = (u16*)(ws + 102236160);          // 0.5 MB

  cast_bf16<<<768, 256, 0, stream>>>(wq, wqb);          // 1536*512
  cast_bf16<<<256, 256, 0, stream>>>(wp, wpb);          // 512*512
  gn_ct<<<256, 256, 0, stream>>>(x, g1, be1, xn);
  // qkv[b][t][o] = sum_c xn[b][t][c] * Wq[o][c] + bq[o]
  gemm_tn<1, 1, 0><<<dim3(12, 16, 8), 256, 0, stream>>>(
      xn, (long)2048 * 512, wqb, 0, bq, nullptr, 0, qkvb, (long)2048 * 1536, 512);
  attn<<<dim3(16, 64), 256, 0, stream>>>(qkvb, a);
  gn_tc<<<256, 256, 0, stream>>>(a, g2, be2, hn);
  // out[b][o][t] = x[b][o][t] + bp[o] + sum_c Wp[o][c] * hn[b][t][c]
  gemm_tn<0, 0, 1><<<dim3(16, 4, 8), 256, 0, stream>>>(
      wpb, 0, hn, (long)2048 * 512, bp, x, (long)512 * 2048, d_out, (long)512 * 2048, 512);
}

// Round 2
// 345.134 us; speedup vs baseline: 1.4680x; 1.4680x over previous
//
#include <hip/hip_runtime.h>

typedef unsigned short u16;
typedef unsigned int   u32;
typedef __attribute__((ext_vector_type(8))) short short8;
typedef __attribute__((ext_vector_type(4))) float floatx4;

// ---------- helpers ----------
__device__ inline u16 f2bf(float x) {
  union { float f; unsigned u; } v; v.f = x;
  unsigned r = v.u + 0x7FFFu + ((v.u >> 16) & 1u);   // RNE
  return (u16)(r >> 16);
}
__device__ inline void cp16(u16* dst, const u16* src) {
  *reinterpret_cast<float4*>(dst) = *reinterpret_cast<const float4*>(src);
}
__device__ inline short8 ld8(const u16* p) {
  return *reinterpret_cast<const short8*>(p);
}

// ---------- weight cast fp32 -> bf16 ----------
__global__ __launch_bounds__(256) void cast_bf16(const float* __restrict__ src,
                                                 u16* __restrict__ dst) {
  int i = blockIdx.x * 256 + threadIdx.x;
  float4 v = reinterpret_cast<const float4*>(src)[i];
  union { u16 u[4]; float2 f; } w;
  w.u[0] = f2bf(v.x); w.u[1] = f2bf(v.y); w.u[2] = f2bf(v.z); w.u[3] = f2bf(v.w);
  reinterpret_cast<float2*>(dst)[i] = w.f;
}

// ---------- GroupNorm 1: x (B,C,T) fp32 -> xn (B,T,C) bf16 ----------
__global__ __launch_bounds__(256) void gn_ct(const float* __restrict__ x,
                                             const float* __restrict__ gamma,
                                             const float* __restrict__ beta,
                                             u16* __restrict__ xn) {
  int b = blockIdx.x >> 5, g = blockIdx.x & 31;
  const float* base = x + ((long)b * 512 + g * 16) * 2048;
  float s = 0.f, ss = 0.f;
  for (int i = threadIdx.x; i < 8192; i += 256) {
    float4 v = reinterpret_cast<const float4*>(base)[i];
    s  += v.x + v.y + v.z + v.w;
    ss += v.x * v.x + v.y * v.y + v.z * v.z + v.w * v.w;
  }
  #pragma unroll
  for (int d = 1; d < 64; d <<= 1) { s += __shfl_xor(s, d); ss += __shfl_xor(ss, d); }
  __shared__ float red[8];
  int wave = threadIdx.x >> 6, lane = threadIdx.x & 63;
  if (lane == 0) { red[wave] = s; red[wave + 4] = ss; }
  __syncthreads();
  s  = red[0] + red[1] + red[2] + red[3];
  ss = red[4] + red[5] + red[6] + red[7];
  float mean = s * (1.f / 32768.f);
  float var  = ss * (1.f / 32768.f) - mean * mean;
  float rstd = rsqrtf(var + 1e-5f);
  float ga[16], be[16];
  #pragma unroll
  for (int c = 0; c < 16; c++) {
    float gm = gamma[g * 16 + c];
    ga[c] = gm * rstd;
    be[c] = beta[g * 16 + c] - mean * rstd * gm;
  }
  u16* ob = xn + (long)b * 2048 * 512 + g * 16;
  for (int t = threadIdx.x; t < 2048; t += 256) {
    union { u16 u[8]; float4 f; } w0, w1;
    #pragma unroll
    for (int c = 0; c < 8; c++)  w0.u[c]     = f2bf(base[c * 2048 + t] * ga[c] + be[c]);
    #pragma unroll
    for (int c = 8; c < 16; c++) w1.u[c - 8] = f2bf(base[c * 2048 + t] * ga[c] + be[c]);
    u16* dst = ob + (long)t * 512;
    *reinterpret_cast<float4*>(dst)     = w0.f;
    *reinterpret_cast<float4*>(dst + 8) = w1.f;
  }
}

// ---------- GroupNorm 2: a (B,T,C) fp32 -> hn (B,T,C) bf16 ----------
__global__ __launch_bounds__(256) void gn_tc(const float* __restrict__ a,
                                             const float* __restrict__ gamma,
                                             const float* __restrict__ beta,
                                             u16* __restrict__ hn) {
  int b = blockIdx.x >> 5, g = blockIdx.x & 31;
  const float* base = a + (long)b * 2048 * 512 + g * 16;
  float s = 0.f, ss = 0.f;
  for (int t = threadIdx.x; t < 2048; t += 256) {
    const float4* p = reinterpret_cast<const float4*>(base + (long)t * 512);
    #pragma unroll
    for (int j = 0; j < 4; j++) {
      float4 v = p[j];
      s  += v.x + v.y + v.z + v.w;
      ss += v.x * v.x + v.y * v.y + v.z * v.z + v.w * v.w;
    }
  }
  #pragma unroll
  for (int d = 1; d < 64; d <<= 1) { s += __shfl_xor(s, d); ss += __shfl_xor(ss, d); }
  __shared__ float red[8];
  int wave = threadIdx.x >> 6, lane = threadIdx.x & 63;
  if (lane == 0) { red[wave] = s; red[wave + 4] = ss; }
  __syncthreads();
  s  = red[0] + red[1] + red[2] + red[3];
  ss = red[4] + red[5] + red[6] + red[7];
  float mean = s * (1.f / 32768.f);
  float var  = ss * (1.f / 32768.f) - mean * mean;
  float rstd = rsqrtf(var + 1e-5f);
  float ga[16], be[16];
  #pragma unroll
  for (int c = 0; c < 16; c++) {
    float gm = gamma[g * 16 + c];
    ga[c] = gm * rstd;
    be[c] = beta[g * 16 + c] - mean * rstd * gm;
  }
  u16* ob = hn + (long)b * 2048 * 512 + g * 16;
  for (int t = threadIdx.x; t < 2048; t += 256) {
    const float* p = base + (long)t * 512;
    union { u16 u[8]; float4 f; } w0, w1;
    #pragma unroll
    for (int c = 0; c < 8; c++)  w0.u[c]     = f2bf(p[c] * ga[c] + be[c]);
    #pragma unroll
    for (int c = 8; c < 16; c++) w1.u[c - 8] = f2bf(p[c] * ga[c] + be[c]);
    u16* dst = ob + (long)t * 512;
    *reinterpret_cast<float4*>(dst)     = w0.f;
    *reinterpret_cast<float4*>(dst + 8) = w1.f;
  }
}

// ---------- unified TN GEMM: D[m][n] = sum_k A[m][k] * Bt[n][k] ----------
// QKV==1: out = qkv bf16 (b,t,1536), q-channels pre-scaled by 0.125*log2e,
//         v-channels routed to Vt (B,NH,64,T) as packed 8B stores.
// QKV==0: out = fp32 (b, m, N) with bias[m] + residual.
#define LDK 40
template<int QKV>
__global__ __launch_bounds__(256) void gemm_tn(
    const u16* __restrict__ A, long abst,
    const u16* __restrict__ Bt, long bbst,
    const float* __restrict__ bias,
    const float* __restrict__ resid, long rbst,
    void* __restrict__ outp, long obst,
    u16* __restrict__ vtp, int K) {
  __shared__ __align__(16) u16 As[128 * LDK];
  __shared__ __align__(16) u16 Bs[128 * LDK];
  const int tid = threadIdx.x;
  const int m0 = blockIdx.y * 128, n0 = blockIdx.x * 128;
  const int N = gridDim.x * 128;
  const long bz = blockIdx.z;
  const u16* Ab = A + bz * abst + (long)m0 * K;
  const u16* Bb = Bt + bz * bbst + (long)n0 * K;
  const int sr = tid >> 2, so = (tid & 3) * 8;
  const int lane = tid & 63, wave = tid >> 6;
  const int wm = (wave & 1) * 64, wn = (wave >> 1) * 64;
  const int l15 = lane & 15, quad = lane >> 4;

  floatx4 acc[4][4];
  #pragma unroll
  for (int i = 0; i < 4; i++)
    #pragma unroll
    for (int j = 0; j < 4; j++) acc[i][j] = (floatx4){0.f, 0.f, 0.f, 0.f};

  for (int k0 = 0; k0 < K; k0 += 32) {
    __syncthreads();
    cp16(&As[sr * LDK + so],        Ab + (long)sr * K + k0 + so);
    cp16(&As[(sr + 64) * LDK + so], Ab + (long)(sr + 64) * K + k0 + so);
    cp16(&Bs[sr * LDK + so],        Bb + (long)sr * K + k0 + so);
    cp16(&Bs[(sr + 64) * LDK + so], Bb + (long)(sr + 64) * K + k0 + so);
    __syncthreads();
    short8 af[4], bf[4];
    #pragma unroll
    for (int i = 0; i < 4; i++) af[i] = ld8(&As[(wm + i * 16 + l15) * LDK + quad * 8]);
    #pragma unroll
    for (int i = 0; i < 4; i++) bf[i] = ld8(&Bs[(wn + i * 16 + l15) * LDK + quad * 8]);
    #pragma unroll
    for (int mi = 0; mi < 4; mi++)
      #pragma unroll
      for (int ni = 0; ni < 4; ni++)
        acc[mi][ni] = __builtin_amdgcn_mfma_f32_16x16x32_bf16(af[mi], bf[ni], acc[mi][ni], 0, 0, 0);
  }

  if (QKV) {
    u16* D  = (u16*)outp + bz * obst;
    u16* VT = vtp + bz * (8L * 64 * 2048);
    #pragma unroll
    for (int ni = 0; ni < 4; ni++) {
      int nb = n0 + wn + ni * 16;              // tile base (uniform)
      int region = (nb >> 6) % 3;              // 0=q, 1=k, 2=v
      int n = nb + l15;
      float bn = bias[n];
      if (region == 2) {
        int hh = n / 192, c = (n % 192) - 128;
        u16* vrow = VT + ((long)hh * 64 + c) * 2048 + m0 + wm;
        #pragma unroll
        for (int mi = 0; mi < 4; mi++) {
          union { u16 u[4]; float2 f; } pk;
          #pragma unroll
          for (int r = 0; r < 4; r++) pk.u[r] = f2bf(acc[mi][ni][r] + bn);
          *reinterpret_cast<float2*>(vrow + mi * 16 + quad * 4) = pk.f;
        }
      } else {
        float sc = (region == 0) ? 0.180336880f : 1.f;   // 0.125 * log2(e)
        #pragma unroll
        for (int mi = 0; mi < 4; mi++)
          #pragma unroll
          for (int r = 0; r < 4; r++) {
            int m = m0 + wm + mi * 16 + quad * 4 + r;
            D[(long)m * 1536 + n] = f2bf((acc[mi][ni][r] + bn) * sc);
          }
      }
    }
  } else {
    float* D = (float*)outp + bz * obst;
    const float* R = resid + bz * rbst;
    #pragma unroll
    for (int mi = 0; mi < 4; mi++)
      #pragma unroll
      for (int r = 0; r < 4; r++) {
        int m = m0 + wm + mi * 16 + quad * 4 + r;
        float bm = bias[m];
        #pragma unroll
        for (int ni = 0; ni < 4; ni++) {
          int n = n0 + wn + ni * 16 + l15;
          long idx = (long)m * N + n;
          D[idx] = acc[mi][ni][r] + bm + R[idx];
        }
      }
  }
}

// ---------- flash attention (S^T formulation) ----------
// qkv: (B,T,1536) bf16, Q pre-scaled by 0.125*log2e; vt: (B,NH,64,T) bf16.
// Block: 256 tq for one (b,h); 4 waves x 64 tq; KV tiles of 64.
// S^T = K Q^T  (C-layout: row=tk, col=tq) -> per-lane softmax cols,
// packed b64 P writes; O^T = V^T P^T (C-layout: row=c, col=tq).
#define LDA 72
__global__ __launch_bounds__(256, 2) void attn(const u16* __restrict__ qkv,
                                               const u16* __restrict__ vt,
                                               float* __restrict__ aout) {
  __shared__ __align__(16) u16 Ps[256 * LDA];   // Q at start, then P (wave-private rows)
  __shared__ __align__(16) u16 Ks[64 * LDA];
  __shared__ __align__(16) u16 Vs[64 * LDA];
  const int tid = threadIdx.x, lane = tid & 63, wave = tid >> 6;
  const int l15 = lane & 15, quad = lane >> 4;
  const int b = blockIdx.y >> 3, h = blockIdx.y & 7;
  const int t0 = blockIdx.x * 256;
  const u16* qbase = qkv + (long)b * 2048 * 1536 + h * 192;
  const u16* vbase = vt + (long)(b * 8 + h) * 64 * 2048;

  // stage Q (256 x 64)
  for (int i = tid; i < 2048; i += 256) {
    int rr = i >> 3, off = (i & 7) * 8;
    cp16(&Ps[rr * LDA + off], qbase + (long)(t0 + rr) * 1536 + off);
  }
  __syncthreads();
  short8 qf[4][2];
  #pragma unroll
  for (int tqi = 0; tqi < 4; tqi++)
    #pragma unroll
    for (int ks = 0; ks < 2; ks++)
      qf[tqi][ks] = ld8(&Ps[(wave * 64 + tqi * 16 + l15) * LDA + ks * 32 + quad * 8]);

  float m_i[4], l_i[4];
  floatx4 accO[4][4];   // [ci][tqi]: row=c, col=tq
  #pragma unroll
  for (int tqi = 0; tqi < 4; tqi++) { m_i[tqi] = -1e30f; l_i[tqi] = 0.f; }
  #pragma unroll
  for (int ci = 0; ci < 4; ci++)
    #pragma unroll
    for (int tqi = 0; tqi < 4; tqi++) accO[ci][tqi] = (floatx4){0.f, 0.f, 0.f, 0.f};

  for (int s0 = 0; s0 < 2048; s0 += 64) {
    __syncthreads();
    for (int i = tid; i < 512; i += 256) {
      int rr = i >> 3, off = (i & 7) * 8;
      cp16(&Ks[rr * LDA + off], qbase + (long)(s0 + rr) * 1536 + 64 + off);
      cp16(&Vs[rr * LDA + off], vbase + (long)rr * 2048 + s0 + off);
    }
    __syncthreads();

    // S^T[tk][tq] = sum_c K[tk][c] * Q[tq][c]
    floatx4 sacc[4][4];   // [tki][tqi]
    #pragma unroll
    for (int i = 0; i < 4; i++)
      #pragma unroll
      for (int j = 0; j < 4; j++) sacc[i][j] = (floatx4){0.f, 0.f, 0.f, 0.f};
    #pragma unroll
    for (int ks = 0; ks < 2; ks++) {
      short8 kf[4];
      #pragma unroll
      for (int tki = 0; tki < 4; tki++)
        kf[tki] = ld8(&Ks[(tki * 16 + l15) * LDA + ks * 32 + quad * 8]);
      #pragma unroll
      for (int tki = 0; tki < 4; tki++)
        #pragma unroll
        for (int tqi = 0; tqi < 4; tqi++)
          sacc[tki][tqi] = __builtin_amdgcn_mfma_f32_16x16x32_bf16(kf[tki], qf[tqi][ks], sacc[tki][tqi], 0, 0, 0);
    }

    // online softmax over tk (per-lane column tq = tqi*16 + l15)
    #pragma unroll
    for (int tqi = 0; tqi < 4; tqi++) {
      float mx = -1e30f;
      #pragma unroll
      for (int tki = 0; tki < 4; tki++)
        #pragma unroll
        for (int r = 0; r < 4; r++) mx = fmaxf(mx, sacc[tki][tqi][r]);
      mx = fmaxf(mx, __shfl_xor(mx, 16));
      mx = fmaxf(mx, __shfl_xor(mx, 32));
      float mn = fmaxf(m_i[tqi], mx);
      float al = __builtin_amdgcn_exp2f(m_i[tqi] - mn);
      m_i[tqi] = mn;
      float rs = 0.f;
      #pragma unroll
      for (int tki = 0; tki < 4; tki++)
        #pragma unroll
        for (int r = 0; r < 4; r++) {
          float p = __builtin_amdgcn_exp2f(sacc[tki][tqi][r] - mn);
          sacc[tki][tqi][r] = p;
          rs += p;
        }
      rs += __shfl_xor(rs, 16);
      rs += __shfl_xor(rs, 32);
      l_i[tqi] = l_i[tqi] * al + rs;
      #pragma unroll
      for (int ci = 0; ci < 4; ci++)
        #pragma unroll
        for (int r = 0; r < 4; r++) accO[ci][tqi][r] *= al;
      // P pack (bf16 truncation) + b64 write: 4 consecutive tk per lane
      u16* prow = &Ps[(wave * 64 + tqi * 16 + l15) * LDA];
      #pragma unroll
      for (int tki = 0; tki < 4; tki++) {
        u32 a0 = __float_as_uint(sacc[tki][tqi][0]);
        u32 a1 = __float_as_uint(sacc[tki][tqi][1]);
        u32 a2 = __float_as_uint(sacc[tki][tqi][2]);
        u32 a3 = __float_as_uint(sacc[tki][tqi][3]);
        union { u32 u[2]; float2 f; } pk;
        pk.u[0] = (a0 >> 16) | (a1 & 0xFFFF0000u);
        pk.u[1] = (a2 >> 16) | (a3 & 0xFFFF0000u);
        *reinterpret_cast<float2*>(prow + tki * 16 + quad * 4) = pk.f;
      }
    }

    // O^T[c][tq] += sum_tk V^T[c][tk] * P[tq][tk]
    #pragma unroll
    for (int ks = 0; ks < 2; ks++) {
      short8 vf[4], pf[4];
      #pragma unroll
      for (int ci = 0; ci < 4; ci++)
        vf[ci] = ld8(&Vs[(ci * 16 + l15) * LDA + ks * 32 + quad * 8]);
      #pragma unroll
      for (int tqi = 0; tqi < 4; tqi++)
        pf[tqi] = ld8(&Ps[(wave * 64 + tqi * 16 + l15) * LDA + ks * 32 + quad * 8]);
      #pragma unroll
      for (int ci = 0; ci < 4; ci++)
        #pragma unroll
        for (int tqi = 0; tqi < 4; tqi++)
          accO[ci][tqi] = __builtin_amdgcn_mfma_f32_16x16x32_bf16(vf[ci], pf[tqi], accO[ci][tqi], 0, 0, 0);
    }
  }

  // epilogue: normalize, write a (B,T,C) fp32; lane holds 4 consecutive c
  float* ob = aout + ((long)b * 2048 + t0 + wave * 64) * 512 + h * 64;
  #pragma unroll
  for (int tqi = 0; tqi < 4; tqi++) {
    float invl = 1.f / l_i[tqi];
    #pragma unroll
    for (int ci = 0; ci < 4; ci++) {
      float4 v;
      v.x = accO[ci][tqi][0] * invl;
      v.y = accO[ci][tqi][1] * invl;
      v.z = accO[ci][tqi][2] * invl;
      v.w = accO[ci][tqi][3] * invl;
      *reinterpret_cast<float4*>(ob + (long)(tqi * 16 + l15) * 512 + ci * 16 + quad * 4) = v;
    }
  }
}

// ---------- launch ----------
extern "C" void kernel_launch(void* const* d_in, const int* in_sizes, int n_in,
                              void* d_out, int out_size, void* d_ws, size_t ws_size,
                              hipStream_t stream) {
  const float* x   = (const float*)d_in[0];
  const float* g1  = (const float*)d_in[1];
  const float* be1 = (const float*)d_in[2];
  const float* wq  = (const float*)d_in[3];
  const float* bq  = (const float*)d_in[4];
  const float* g2  = (const float*)d_in[5];
  const float* be2 = (const float*)d_in[6];
  const float* wp  = (const float*)d_in[7];
  const float* bp  = (const float*)d_in[8];

  char* ws = (char*)d_ws;
  u16*   xn   = (u16*)ws;                        // 16.8 MB, dead after gemm1
  float* a    = (float*)ws;                      // 33.5 MB, attn -> gn2
  u16*   qkvb = (u16*)(ws + 33554432);           // 50.3 MB (q/k live, v-holes unused)
  u16*   hn   = (u16*)(ws + 83886080);           // 16.8 MB, gn2 -> gemm2
  u16*   vtb  = hn;                              // alias: Vt lifetime gemm1 -> attn
  u16*   wqb  = (u16*)(ws + 100663296);          // 1.6 MB
  u16*   wpb  = (u16*)(ws + 102236160);          // 0.5 MB

  cast_bf16<<<768, 256, 0, stream>>>(wq, wqb);
  cast_bf16<<<256, 256, 0, stream>>>(wp, wpb);
  gn_ct<<<256, 256, 0, stream>>>(x, g1, be1, xn);
  // qkv[b][t][o] = sum_c xn[b][t][c] * Wq[o][c] + bq[o]  (+ q-scale, v->Vt)
  gemm_tn<1><<<dim3(12, 16, 8), 256, 0, stream>>>(
      xn, (long)2048 * 512, wqb, 0, bq, nullptr, 0, qkvb, (long)2048 * 1536, vtb, 512);
  attn<<<dim3(8, 64), 256, 0, stream>>>(qkvb, vtb, a);
  gn_tc<<<256, 256, 0, stream>>>(a, g2, be2, hn);
  // out[b][o][t] = x[b][o][t] + bp[o] + sum_c Wp[o][c] * hn[b][t][c]
  gemm_tn<0><<<dim3(16, 4, 8), 256, 0, stream>>>(
      wpb, 0, hn, (long)2048 * 512, bp, x, (long)512 * 2048, d_out, (long)512 * 2048, nullptr, 512);
}

// Round 3
// 323.718 us; speedup vs baseline: 1.5651x; 1.0662x over previous
//
#include <hip/hip_runtime.h>

typedef unsigned short u16;
typedef unsigned int   u32;
typedef __attribute__((ext_vector_type(8))) short short8;
typedef __attribute__((ext_vector_type(4))) float floatx4;

// ---------- helpers ----------
__device__ inline u16 f2bf(float x) {
  union { float f; unsigned u; } v; v.f = x;
  unsigned r = v.u + 0x7FFFu + ((v.u >> 16) & 1u);   // RNE
  return (u16)(r >> 16);
}
__device__ inline float bf2f(short s) {
  union { u32 u; float f; } v; v.u = ((u32)(u16)s) << 16; return v.f;
}
__device__ inline short8 ld8(const u16* p) {
  return *reinterpret_cast<const short8*>(p);
}
// async global->LDS DMA, 16B per lane; lds dest = wave-uniform base + lane*16
__device__ inline void async_ld16(const u16* g, u16* l) {
  unsigned loff = (unsigned)(unsigned long long)(void*)l;
  __builtin_amdgcn_global_load_lds(reinterpret_cast<const unsigned*>(g),
      reinterpret_cast<__attribute__((address_space(3))) unsigned*>(loff), 16, 0, 0);
}

// ---------- weight cast fp32 -> bf16 ----------
__global__ __launch_bounds__(256) void cast_bf16(const float* __restrict__ src,
                                                 u16* __restrict__ dst) {
  int i = blockIdx.x * 256 + threadIdx.x;
  float4 v = reinterpret_cast<const float4*>(src)[i];
  union { u16 u[4]; float2 f; } w;
  w.u[0] = f2bf(v.x); w.u[1] = f2bf(v.y); w.u[2] = f2bf(v.z); w.u[3] = f2bf(v.w);
  reinterpret_cast<float2*>(dst)[i] = w.f;
}

// ---------- GroupNorm 1: x (B,C,T) fp32 -> xn (B,T,C) bf16 ----------
__global__ __launch_bounds__(256) void gn_ct(const float* __restrict__ x,
                                             const float* __restrict__ gamma,
                                             const float* __restrict__ beta,
                                             u16* __restrict__ xn) {
  int b = blockIdx.x >> 5, g = blockIdx.x & 31;
  const float* base = x + ((long)b * 512 + g * 16) * 2048;
  float s = 0.f, ss = 0.f;
  for (int i = threadIdx.x; i < 8192; i += 256) {
    float4 v = reinterpret_cast<const float4*>(base)[i];
    s  += v.x + v.y + v.z + v.w;
    ss += v.x * v.x + v.y * v.y + v.z * v.z + v.w * v.w;
  }
  #pragma unroll
  for (int d = 1; d < 64; d <<= 1) { s += __shfl_xor(s, d); ss += __shfl_xor(ss, d); }
  __shared__ float red[8];
  int wave = threadIdx.x >> 6, lane = threadIdx.x & 63;
  if (lane == 0) { red[wave] = s; red[wave + 4] = ss; }
  __syncthreads();
  s  = red[0] + red[1] + red[2] + red[3];
  ss = red[4] + red[5] + red[6] + red[7];
  float mean = s * (1.f / 32768.f);
  float var  = ss * (1.f / 32768.f) - mean * mean;
  float rstd = rsqrtf(var + 1e-5f);
  float ga[16], be[16];
  #pragma unroll
  for (int c = 0; c < 16; c++) {
    float gm = gamma[g * 16 + c];
    ga[c] = gm * rstd;
    be[c] = beta[g * 16 + c] - mean * rstd * gm;
  }
  u16* ob = xn + (long)b * 2048 * 512 + g * 16;
  for (int t = threadIdx.x; t < 2048; t += 256) {
    union { u16 u[8]; float4 f; } w0, w1;
    #pragma unroll
    for (int c = 0; c < 8; c++)  w0.u[c]     = f2bf(base[c * 2048 + t] * ga[c] + be[c]);
    #pragma unroll
    for (int c = 8; c < 16; c++) w1.u[c - 8] = f2bf(base[c * 2048 + t] * ga[c] + be[c]);
    u16* dst = ob + (long)t * 512;
    *reinterpret_cast<float4*>(dst)     = w0.f;
    *reinterpret_cast<float4*>(dst + 8) = w1.f;
  }
}

// ---------- GroupNorm 2: a (B,T,C) bf16 -> hn (B,T,C) bf16 ----------
__global__ __launch_bounds__(256) void gn_tc(const u16* __restrict__ a,
                                             const float* __restrict__ gamma,
                                             const float* __restrict__ beta,
                                             u16* __restrict__ hn) {
  int b = blockIdx.x >> 5, g = blockIdx.x & 31;
  const u16* base = a + (long)b * 2048 * 512 + g * 16;
  float s = 0.f, ss = 0.f;
  for (int t = threadIdx.x; t < 2048; t += 256) {
    const u16* p = base + (long)t * 512;
    short8 v0 = ld8(p), v1 = ld8(p + 8);
    #pragma unroll
    for (int j = 0; j < 8; j++) {
      float f0 = bf2f(v0[j]), f1 = bf2f(v1[j]);
      s += f0 + f1; ss += f0 * f0 + f1 * f1;
    }
  }
  #pragma unroll
  for (int d = 1; d < 64; d <<= 1) { s += __shfl_xor(s, d); ss += __shfl_xor(ss, d); }
  __shared__ float red[8];
  int wave = threadIdx.x >> 6, lane = threadIdx.x & 63;
  if (lane == 0) { red[wave] = s; red[wave + 4] = ss; }
  __syncthreads();
  s  = red[0] + red[1] + red[2] + red[3];
  ss = red[4] + red[5] + red[6] + red[7];
  float mean = s * (1.f / 32768.f);
  float var  = ss * (1.f / 32768.f) - mean * mean;
  float rstd = rsqrtf(var + 1e-5f);
  float ga[16], be[16];
  #pragma unroll
  for (int c = 0; c < 16; c++) {
    float gm = gamma[g * 16 + c];
    ga[c] = gm * rstd;
    be[c] = beta[g * 16 + c] - mean * rstd * gm;
  }
  u16* ob = hn + (long)b * 2048 * 512 + g * 16;
  for (int t = threadIdx.x; t < 2048; t += 256) {
    const u16* p = base + (long)t * 512;
    short8 v0 = ld8(p), v1 = ld8(p + 8);
    union { u16 u[8]; float4 f; } w0, w1;
    #pragma unroll
    for (int c = 0; c < 8; c++)  w0.u[c] = f2bf(bf2f(v0[c]) * ga[c] + be[c]);
    #pragma unroll
    for (int c = 0; c < 8; c++)  w1.u[c] = f2bf(bf2f(v1[c]) * ga[c + 8] + be[c + 8]);
    u16* dst = ob + (long)t * 512;
    *reinterpret_cast<float4*>(dst)     = w0.f;
    *reinterpret_cast<float4*>(dst + 8) = w1.f;
  }
}

// ---------- unified TN GEMM: D[m][n] = sum_k A[m][k] * Bt[n][k] ----------
// m97 pattern: unpadded 128x32 LDS tiles, global_load_lds width=16 staging.
// QKV==1: out = qkv bf16 (b,t,1536), q-channels pre-scaled by 0.125*log2e,
//         v-channels routed to Vt (B,NH,64,T) as packed 8B stores.
// QKV==0: out = fp32 (b, m, N) with bias[m] + residual.
template<int QKV>
__global__ __launch_bounds__(256) void gemm_tn(
    const u16* __restrict__ A, long abst,
    const u16* __restrict__ Bt, long bbst,
    const float* __restrict__ bias,
    const float* __restrict__ resid, long rbst,
    void* __restrict__ outp, long obst,
    u16* __restrict__ vtp, int K) {
  __shared__ __align__(16) u16 As[128 * 32];
  __shared__ __align__(16) u16 Bs[128 * 32];
  const int tid = threadIdx.x;
  const int m0 = blockIdx.y * 128, n0 = blockIdx.x * 128;
  const int N = gridDim.x * 128;
  const long bz = blockIdx.z;
  const u16* Ab = A + bz * abst + (long)m0 * K;
  const u16* Bb = Bt + bz * bbst + (long)n0 * K;
  const int lane = tid & 63, wave = tid >> 6;
  const int wm = (wave & 1) * 64, wn = (wave >> 1) * 64;
  const int l15 = lane & 15, quad = lane >> 4;
  // per-thread staging source ptrs (row = tid>>2, chunk = tid&3), two 64-row halves
  const u16* ag[2]; const u16* bg[2];
  const int ldso = wave * 512;
  #pragma unroll
  for (int half = 0; half < 2; half++) {
    int r = half * 64 + (tid >> 2);
    ag[half] = Ab + (long)r * K + (tid & 3) * 8;
    bg[half] = Bb + (long)r * K + (tid & 3) * 8;
  }

  floatx4 acc[4][4];
  #pragma unroll
  for (int i = 0; i < 4; i++)
    #pragma unroll
    for (int j = 0; j < 4; j++) acc[i][j] = (floatx4){0.f, 0.f, 0.f, 0.f};

  for (int k0 = 0; k0 < K; k0 += 32) {
    __syncthreads();
    #pragma unroll
    for (int half = 0; half < 2; half++) {
      async_ld16(ag[half] + k0, &As[half * 2048 + ldso]);
      async_ld16(bg[half] + k0, &Bs[half * 2048 + ldso]);
    }
    __syncthreads();
    short8 af[4], bfr[4];
    #pragma unroll
    for (int i = 0; i < 4; i++) af[i]  = ld8(&As[(wm + i * 16 + l15) * 32 + quad * 8]);
    #pragma unroll
    for (int i = 0; i < 4; i++) bfr[i] = ld8(&Bs[(wn + i * 16 + l15) * 32 + quad * 8]);
    #pragma unroll
    for (int mi = 0; mi < 4; mi++)
      #pragma unroll
      for (int ni = 0; ni < 4; ni++)
        acc[mi][ni] = __builtin_amdgcn_mfma_f32_16x16x32_bf16(af[mi], bfr[ni], acc[mi][ni], 0, 0, 0);
  }

  if (QKV) {
    u16* D  = (u16*)outp + bz * obst;
    u16* VT = vtp + bz * (8L * 64 * 2048);
    #pragma unroll
    for (int ni = 0; ni < 4; ni++) {
      int nb = n0 + wn + ni * 16;              // tile base (uniform)
      int region = (nb >> 6) % 3;              // 0=q, 1=k, 2=v
      int n = nb + l15;
      float bn = bias[n];
      if (region == 2) {
        int hh = n / 192, c = (n % 192) - 128;
        u16* vrow = VT + ((long)hh * 64 + c) * 2048 + m0 + wm;
        #pragma unroll
        for (int mi = 0; mi < 4; mi++) {
          union { u16 u[4]; float2 f; } pk;
          #pragma unroll
          for (int r = 0; r < 4; r++) pk.u[r] = f2bf(acc[mi][ni][r] + bn);
          *reinterpret_cast<float2*>(vrow + mi * 16 + quad * 4) = pk.f;
        }
      } else {
        float sc = (region == 0) ? 0.180336880f : 1.f;   // 0.125 * log2(e)
        #pragma unroll
        for (int mi = 0; mi < 4; mi++)
          #pragma unroll
          for (int r = 0; r < 4; r++) {
            int m = m0 + wm + mi * 16 + quad * 4 + r;
            D[(long)m * 1536 + n] = f2bf((acc[mi][ni][r] + bn) * sc);
          }
      }
    }
  } else {
    float* D = (float*)outp + bz * obst;
    const float* R = resid + bz * rbst;
    #pragma unroll
    for (int mi = 0; mi < 4; mi++)
      #pragma unroll
      for (int r = 0; r < 4; r++) {
        int m = m0 + wm + mi * 16 + quad * 4 + r;
        float bm = bias[m];
        #pragma unroll
        for (int ni = 0; ni < 4; ni++) {
          int n = n0 + wn + ni * 16 + l15;
          long idx = (long)m * N + n;
          D[idx] = acc[mi][ni][r] + bm + R[idx];
        }
      }
  }
}

// ---------- flash attention (S^T formulation, async dbuf K/V) ----------
// qkv: (B,T,1536) bf16, Q pre-scaled by 0.125*log2e; vt: (B,NH,64,T) bf16.
// Block: 256 tq for one (b,h); 4 waves x 64 tq; KV tiles of 64, double-buffered.
// LDS tiles unpadded 64 rows x 8 chunks(16B), XOR-swizzled: phys_c = c ^ (row&7).
__global__ __launch_bounds__(256, 2) void attn(const u16* __restrict__ qkv,
                                               const u16* __restrict__ vt,
                                               u16* __restrict__ aout) {
  __shared__ __align__(16) u16 Ps[256 * 64];     // 32KB, P (wave-private rows, swizzled)
  __shared__ __align__(16) u16 Ks[2][64 * 64];   // 2x8KB
  __shared__ __align__(16) u16 Vs[2][64 * 64];   // 2x8KB
  const int tid = threadIdx.x, lane = tid & 63, wave = tid >> 6;
  const int l15 = lane & 15, quad = lane >> 4;
  const int sw = l15 & 7;                        // row-swizzle key
  const int b = blockIdx.y >> 3, h = blockIdx.y & 7;
  const int t0 = blockIdx.x * 256;
  const u16* qbase = qkv + (long)b * 2048 * 1536 + h * 192;
  const u16* vbase = vt + (long)(b * 8 + h) * 64 * 2048;

  // Q fragments straight from global (A-layout: 16B/lane)
  short8 qf[4][2];
  #pragma unroll
  for (int tqi = 0; tqi < 4; tqi++)
    #pragma unroll
    for (int ks = 0; ks < 2; ks++)
      qf[tqi][ks] = ld8(qbase + (long)(t0 + wave * 64 + tqi * 16 + l15) * 1536 + ks * 32 + quad * 8);

  // staging source pointers: lane covers phys chunk p, reads logical chunk c = (p&7)^(row&7)
  const u16* kg[2]; const u16* vg[2]; int ldso[2];
  #pragma unroll
  for (int half = 0; half < 2; half++) {
    int p = half * 256 + wave * 64 + lane;
    int row = p >> 3, c = (p & 7) ^ (row & 7);
    kg[half] = qbase + (long)row * 1536 + 64 + c * 8;
    vg[half] = vbase + (long)row * 2048 + c * 8;
    ldso[half] = (half * 256 + wave * 64) * 8;
  }
  #pragma unroll
  for (int half = 0; half < 2; half++) {
    async_ld16(kg[half], &Ks[0][ldso[half]]);
    async_ld16(vg[half], &Vs[0][ldso[half]]);
  }

  float m_i[4], l_i[4];
  floatx4 accO[4][4];   // [ci][tqi]: row=c, col=tq
  #pragma unroll
  for (int tqi = 0; tqi < 4; tqi++) { m_i[tqi] = -1e30f; l_i[tqi] = 0.f; }
  #pragma unroll
  for (int ci = 0; ci < 4; ci++)
    #pragma unroll
    for (int tqi = 0; tqi < 4; tqi++) accO[ci][tqi] = (floatx4){0.f, 0.f, 0.f, 0.f};

  for (int it = 0; it < 32; it++) {
    const u16* kb = Ks[it & 1];
    const u16* vb = Vs[it & 1];
    __syncthreads();                     // publishes tile it; frees buffer it^1
    if (it < 31) {                       // prefetch tile it+1 (drained at next barrier)
      int s1 = (it + 1) * 64;
      u16* kn = Ks[(it & 1) ^ 1];
      u16* vn = Vs[(it & 1) ^ 1];
      #pragma unroll
      for (int half = 0; half < 2; half++) {
        async_ld16(kg[half] + (long)s1 * 1536, &kn[ldso[half]]);
        async_ld16(vg[half] + s1,              &vn[ldso[half]]);
      }
    }

    // S^T[tk][tq] = sum_c K[tk][c] * Q[tq][c]
    floatx4 sacc[4][4];   // [tki][tqi]
    #pragma unroll
    for (int i = 0; i < 4; i++)
      #pragma unroll
      for (int j = 0; j < 4; j++) sacc[i][j] = (floatx4){0.f, 0.f, 0.f, 0.f};
    #pragma unroll
    for (int ks = 0; ks < 2; ks++) {
      short8 kf[4];
      #pragma unroll
      for (int tki = 0; tki < 4; tki++)
        kf[tki] = ld8(&kb[((tki * 16 + l15) << 6) + (((ks * 4 + quad) ^ sw) << 3)]);
      #pragma unroll
      for (int tki = 0; tki < 4; tki++)
        #pragma unroll
        for (int tqi = 0; tqi < 4; tqi++)
          sacc[tki][tqi] = __builtin_amdgcn_mfma_f32_16x16x32_bf16(kf[tki], qf[tqi][ks], sacc[tki][tqi], 0, 0, 0);
    }

    // online softmax over tk (per-lane column tq)
    #pragma unroll
    for (int tqi = 0; tqi < 4; tqi++) {
      float mx = -1e30f;
      #pragma unroll
      for (int tki = 0; tki < 4; tki++)
        #pragma unroll
        for (int r = 0; r < 4; r++) mx = fmaxf(mx, sacc[tki][tqi][r]);
      mx = fmaxf(mx, __shfl_xor(mx, 16));
      mx = fmaxf(mx, __shfl_xor(mx, 32));
      float mo = m_i[tqi];
      float mn = fmaxf(mo, mx);
      m_i[tqi] = mn;
      float rs = 0.f;
      #pragma unroll
      for (int tki = 0; tki < 4; tki++)
        #pragma unroll
        for (int r = 0; r < 4; r++) {
          float p = __builtin_amdgcn_exp2f(sacc[tki][tqi][r] - mn);
          sacc[tki][tqi][r] = p;
          rs += p;
        }
      rs += __shfl_xor(rs, 16);
      rs += __shfl_xor(rs, 32);
      if (__any(mx > mo)) {
        float al = __builtin_amdgcn_exp2f(mo - mn);
        l_i[tqi] = l_i[tqi] * al + rs;
        #pragma unroll
        for (int ci = 0; ci < 4; ci++)
          #pragma unroll
          for (int r = 0; r < 4; r++) accO[ci][tqi][r] *= al;
      } else {
        l_i[tqi] += rs;
      }
      // P write: 4 consecutive tk per 8B store, swizzled chunk
      int prow = (wave * 64 + tqi * 16 + l15) << 6;
      #pragma unroll
      for (int tki = 0; tki < 4; tki++) {
        union { u32 u[2]; float2 f; } pk;
        pk.u[0] = __builtin_amdgcn_perm(__float_as_uint(sacc[tki][tqi][1]),
                                        __float_as_uint(sacc[tki][tqi][0]), 0x07060302);
        pk.u[1] = __builtin_amdgcn_perm(__float_as_uint(sacc[tki][tqi][3]),
                                        __float_as_uint(sacc[tki][tqi][2]), 0x07060302);
        int c16 = tki * 2 + (quad >> 1);
        *reinterpret_cast<float2*>(
            &Ps[prow + ((c16 ^ sw) << 3) + ((quad & 1) << 2)]) = pk.f;
      }
    }

    // O^T[c][tq] += sum_tk V^T[c][tk] * P[tq][tk]  (P wave-private: no barrier)
    #pragma unroll
    for (int ks = 0; ks < 2; ks++) {
      short8 vf[4], pf[4];
      #pragma unroll
      for (int ci = 0; ci < 4; ci++)
        vf[ci] = ld8(&vb[((ci * 16 + l15) << 6) + (((ks * 4 + quad) ^ sw) << 3)]);
      #pragma unroll
      for (int tqi = 0; tqi < 4; tqi++)
        pf[tqi] = ld8(&Ps[((wave * 64 + tqi * 16 + l15) << 6) + (((ks * 4 + quad) ^ sw) << 3)]);
      #pragma unroll
      for (int ci = 0; ci < 4; ci++)
        #pragma unroll
        for (int tqi = 0; tqi < 4; tqi++)
          accO[ci][tqi] = __builtin_amdgcn_mfma_f32_16x16x32_bf16(vf[ci], pf[tqi], accO[ci][tqi], 0, 0, 0);
    }
  }

  // epilogue: normalize, write a (B,T,C) bf16; lane holds 4 consecutive c
  u16* ob = aout + ((long)b * 2048 + t0 + wave * 64) * 512 + h * 64;
  #pragma unroll
  for (int tqi = 0; tqi < 4; tqi++) {
    float invl = 1.f / l_i[tqi];
    #pragma unroll
    for (int ci = 0; ci < 4; ci++) {
      union { u16 u[4]; float2 f; } pk;
      #pragma unroll
      for (int r = 0; r < 4; r++) pk.u[r] = f2bf(accO[ci][tqi][r] * invl);
      *reinterpret_cast<float2*>(ob + (long)(tqi * 16 + l15) * 512 + ci * 16 + quad * 4) = pk.f;
    }
  }
}

// ---------- launch ----------
extern "C" void kernel_launch(void* const* d_in, const int* in_sizes, int n_in,
                              void* d_out, int out_size, void* d_ws, size_t ws_size,
                              hipStream_t stream) {
  const float* x   = (const float*)d_in[0];
  const float* g1  = (const float*)d_in[1];
  const float* be1 = (const float*)d_in[2];
  const float* wq  = (const float*)d_in[3];
  const float* bq  = (const float*)d_in[4];
  const float* g2  = (const float*)d_in[5];
  const float* be2 = (const float*)d_in[6];
  const float* wp  = (const float*)d_in[7];
  const float* bp  = (const float*)d_in[8];

  char* ws = (char*)d_ws;
  u16*   xn   = (u16*)ws;                        // 16.8 MB, dead after gemm1
  u16*   a    = (u16*)ws;                        // bf16 attn out, alias xn (disjoint lifetime)
  u16*   qkvb = (u16*)(ws + 33554432);           // 50.3 MB (q/k live, v-holes unused)
  u16*   hn   = (u16*)(ws + 83886080);           // 16.8 MB, gn2 -> gemm2
  u16*   vtb  = hn;                              // alias: Vt lifetime gemm1 -> attn
  u16*   wqb  = (u16*)(ws + 100663296);          // 1.6 MB
  u16*   wpb  = (u16*)(ws + 102236160);          // 0.5 MB

  cast_bf16<<<768, 256, 0, stream>>>(wq, wqb);
  cast_bf16<<<256, 256, 0, stream>>>(wp, wpb);
  gn_ct<<<256, 256, 0, stream>>>(x, g1, be1, xn);
  // qkv[b][t][o] = sum_c xn[b][t][c] * Wq[o][c] + bq[o]  (+ q-scale, v->Vt)
  gemm_tn<1><<<dim3(12, 16, 8), 256, 0, stream>>>(
      xn, (long)2048 * 512, wqb, 0, bq, nullptr, 0, qkvb, (long)2048 * 1536, vtb, 512);
  attn<<<dim3(8, 64), 256, 0, stream>>>(qkvb, vtb, a);
  gn_tc<<<256, 256, 0, stream>>>(a, g2, be2, hn);
  // out[b][o][t] = x[b][o][t] + bp[o] + sum_c Wp[o][c] * hn[b][t][c]
  gemm_tn<0><<<dim3(16, 4, 8), 256, 0, stream>>>(
      wpb, 0, hn, (long)2048 * 512, bp, x, (long)512 * 2048, d_out, (long)512 * 2048, nullptr, 512);
}

// Round 4
// 283.971 us; speedup vs baseline: 1.7842x; 1.1400x over previous
//
#include <hip/hip_runtime.h>

typedef unsigned short u16;
typedef unsigned int   u32;
typedef __attribute__((ext_vector_type(8))) short short8;
typedef __attribute__((ext_vector_type(4))) float floatx4;

// ---------- helpers ----------
__device__ inline u16 f2bf(float x) {
  union { float f; unsigned u; } v; v.f = x;
  unsigned r = v.u + 0x7FFFu + ((v.u >> 16) & 1u);   // RNE
  return (u16)(r >> 16);
}
__device__ inline float bf2f(short s) {
  union { u32 u; float f; } v; v.u = ((u32)(u16)s) << 16; return v.f;
}
__device__ inline short8 ld8(const u16* p) {
  return *reinterpret_cast<const short8*>(p);
}
// async global->LDS DMA, 16B per lane; lds dest = wave-uniform base + lane*16
__device__ inline void async_ld16(const u16* g, u16* l) {
  unsigned loff = (unsigned)(unsigned long long)(void*)l;
  __builtin_amdgcn_global_load_lds(reinterpret_cast<const unsigned*>(g),
      reinterpret_cast<__attribute__((address_space(3))) unsigned*>(loff), 16, 0, 0);
}

// ---------- weight casts fp32 -> bf16 (both weights, one launch) ----------
__global__ __launch_bounds__(256) void cast_both(const float* __restrict__ s1,
                                                 u16* __restrict__ d1,
                                                 const float* __restrict__ s2,
                                                 u16* __restrict__ d2) {
  const float* src; u16* dst; int i;
  if (blockIdx.x < 768) { src = s1; dst = d1; i = blockIdx.x * 256 + threadIdx.x; }
  else                  { src = s2; dst = d2; i = (blockIdx.x - 768) * 256 + threadIdx.x; }
  float4 v = reinterpret_cast<const float4*>(src)[i];
  union { u16 u[4]; float2 f; } w;
  w.u[0] = f2bf(v.x); w.u[1] = f2bf(v.y); w.u[2] = f2bf(v.z); w.u[3] = f2bf(v.w);
  reinterpret_cast<float2*>(dst)[i] = w.f;
}

// ---------- GroupNorm 1: x (B,C,T) fp32 -> xn (B,T,C) bf16 ----------
// block = (b,g) with 1024 threads (16 waves/CU for latency hiding)
__global__ __launch_bounds__(1024) void gn_ct(const float* __restrict__ x,
                                              const float* __restrict__ gamma,
                                              const float* __restrict__ beta,
                                              u16* __restrict__ xn) {
  int b = blockIdx.x >> 5, g = blockIdx.x & 31;
  const float* base = x + ((long)b * 512 + g * 16) * 2048;
  float s = 0.f, ss = 0.f;
  for (int i = threadIdx.x; i < 8192; i += 1024) {
    float4 v = reinterpret_cast<const float4*>(base)[i];
    s  += v.x + v.y + v.z + v.w;
    ss += v.x * v.x + v.y * v.y + v.z * v.z + v.w * v.w;
  }
  #pragma unroll
  for (int d = 1; d < 64; d <<= 1) { s += __shfl_xor(s, d); ss += __shfl_xor(ss, d); }
  __shared__ float red[32];
  int wave = threadIdx.x >> 6, lane = threadIdx.x & 63;
  if (lane == 0) { red[wave] = s; red[wave + 16] = ss; }
  __syncthreads();
  s = 0.f; ss = 0.f;
  #pragma unroll
  for (int w = 0; w < 16; w++) { s += red[w]; ss += red[w + 16]; }
  float mean = s * (1.f / 32768.f);
  float var  = ss * (1.f / 32768.f) - mean * mean;
  float rstd = rsqrtf(var + 1e-5f);
  float ga[16], be[16];
  #pragma unroll
  for (int c = 0; c < 16; c++) {
    float gm = gamma[g * 16 + c];
    ga[c] = gm * rstd;
    be[c] = beta[g * 16 + c] - mean * rstd * gm;
  }
  u16* ob = xn + (long)b * 2048 * 512 + g * 16;
  for (int t = threadIdx.x; t < 2048; t += 1024) {
    union { u16 u[8]; float4 f; } w0, w1;
    #pragma unroll
    for (int c = 0; c < 8; c++)  w0.u[c]     = f2bf(base[c * 2048 + t] * ga[c] + be[c]);
    #pragma unroll
    for (int c = 8; c < 16; c++) w1.u[c - 8] = f2bf(base[c * 2048 + t] * ga[c] + be[c]);
    u16* dst = ob + (long)t * 512;
    *reinterpret_cast<float4*>(dst)     = w0.f;
    *reinterpret_cast<float4*>(dst + 8) = w1.f;
  }
}

// ---------- GroupNorm 2: a (B,T,C) bf16 -> hn (B,T,C) bf16 ----------
__global__ __launch_bounds__(1024) void gn_tc(const u16* __restrict__ a,
                                              const float* __restrict__ gamma,
                                              const float* __restrict__ beta,
                                              u16* __restrict__ hn) {
  int b = blockIdx.x >> 5, g = blockIdx.x & 31;
  const u16* base = a + (long)b * 2048 * 512 + g * 16;
  float s = 0.f, ss = 0.f;
  for (int t = threadIdx.x; t < 2048; t += 1024) {
    const u16* p = base + (long)t * 512;
    short8 v0 = ld8(p), v1 = ld8(p + 8);
    #pragma unroll
    for (int j = 0; j < 8; j++) {
      float f0 = bf2f(v0[j]), f1 = bf2f(v1[j]);
      s += f0 + f1; ss += f0 * f0 + f1 * f1;
    }
  }
  #pragma unroll
  for (int d = 1; d < 64; d <<= 1) { s += __shfl_xor(s, d); ss += __shfl_xor(ss, d); }
  __shared__ float red[32];
  int wave = threadIdx.x >> 6, lane = threadIdx.x & 63;
  if (lane == 0) { red[wave] = s; red[wave + 16] = ss; }
  __syncthreads();
  s = 0.f; ss = 0.f;
  #pragma unroll
  for (int w = 0; w < 16; w++) { s += red[w]; ss += red[w + 16]; }
  float mean = s * (1.f / 32768.f);
  float var  = ss * (1.f / 32768.f) - mean * mean;
  float rstd = rsqrtf(var + 1e-5f);
  float ga[16], be[16];
  #pragma unroll
  for (int c = 0; c < 16; c++) {
    float gm = gamma[g * 16 + c];
    ga[c] = gm * rstd;
    be[c] = beta[g * 16 + c] - mean * rstd * gm;
  }
  u16* ob = hn + (long)b * 2048 * 512 + g * 16;
  for (int t = threadIdx.x; t < 2048; t += 1024) {
    const u16* p = base + (long)t * 512;
    short8 v0 = ld8(p), v1 = ld8(p + 8);
    union { u16 u[8]; float4 f; } w0, w1;
    #pragma unroll
    for (int c = 0; c < 8; c++)  w0.u[c] = f2bf(bf2f(v0[c]) * ga[c] + be[c]);
    #pragma unroll
    for (int c = 0; c < 8; c++)  w1.u[c] = f2bf(bf2f(v1[c]) * ga[c + 8] + be[c + 8]);
    u16* dst = ob + (long)t * 512;
    *reinterpret_cast<float4*>(dst)     = w0.f;
    *reinterpret_cast<float4*>(dst + 8) = w1.f;
  }
}

// ---------- unified TN GEMM: D[m][n] = sum_k A[m][k] * Bt[n][k] ----------
// m97 pattern: unpadded 128x32 LDS tiles, global_load_lds width=16 staging.
// QKV==1: out = qkv bf16 (b,t,1536), q-channels pre-scaled by 0.125*log2e,
//         v-channels routed to Vt (B,NH,64,T) as packed 8B stores.
// QKV==0: out = fp32 (b, m, N) with bias[m] + residual.
template<int QKV>
__global__ __launch_bounds__(256) void gemm_tn(
    const u16* __restrict__ A, long abst,
    const u16* __restrict__ Bt, long bbst,
    const float* __restrict__ bias,
    const float* __restrict__ resid, long rbst,
    void* __restrict__ outp, long obst,
    u16* __restrict__ vtp, int K) {
  __shared__ __align__(16) u16 As[128 * 32];
  __shared__ __align__(16) u16 Bs[128 * 32];
  const int tid = threadIdx.x;
  const int m0 = blockIdx.y * 128, n0 = blockIdx.x * 128;
  const int N = gridDim.x * 128;
  const long bz = blockIdx.z;
  const u16* Ab = A + bz * abst + (long)m0 * K;
  const u16* Bb = Bt + bz * bbst + (long)n0 * K;
  const int lane = tid & 63, wave = tid >> 6;
  const int wm = (wave & 1) * 64, wn = (wave >> 1) * 64;
  const int l15 = lane & 15, quad = lane >> 4;
  const u16* ag[2]; const u16* bg[2];
  const int ldso = wave * 512;
  #pragma unroll
  for (int half = 0; half < 2; half++) {
    int r = half * 64 + (tid >> 2);
    ag[half] = Ab + (long)r * K + (tid & 3) * 8;
    bg[half] = Bb + (long)r * K + (tid & 3) * 8;
  }

  floatx4 acc[4][4];
  #pragma unroll
  for (int i = 0; i < 4; i++)
    #pragma unroll
    for (int j = 0; j < 4; j++) acc[i][j] = (floatx4){0.f, 0.f, 0.f, 0.f};

  for (int k0 = 0; k0 < K; k0 += 32) {
    __syncthreads();
    #pragma unroll
    for (int half = 0; half < 2; half++) {
      async_ld16(ag[half] + k0, &As[half * 2048 + ldso]);
      async_ld16(bg[half] + k0, &Bs[half * 2048 + ldso]);
    }
    __syncthreads();
    short8 af[4], bfr[4];
    #pragma unroll
    for (int i = 0; i < 4; i++) af[i]  = ld8(&As[(wm + i * 16 + l15) * 32 + quad * 8]);
    #pragma unroll
    for (int i = 0; i < 4; i++) bfr[i] = ld8(&Bs[(wn + i * 16 + l15) * 32 + quad * 8]);
    #pragma unroll
    for (int mi = 0; mi < 4; mi++)
      #pragma unroll
      for (int ni = 0; ni < 4; ni++)
        acc[mi][ni] = __builtin_amdgcn_mfma_f32_16x16x32_bf16(af[mi], bfr[ni], acc[mi][ni], 0, 0, 0);
  }

  if (QKV) {
    u16* D  = (u16*)outp + bz * obst;
    u16* VT = vtp + bz * (8L * 64 * 2048);
    #pragma unroll
    for (int ni = 0; ni < 4; ni++) {
      int nb = n0 + wn + ni * 16;              // tile base (uniform)
      int region = (nb >> 6) % 3;              // 0=q, 1=k, 2=v
      int n = nb + l15;
      float bn = bias[n];
      if (region == 2) {
        int hh = n / 192, c = (n % 192) - 128;
        u16* vrow = VT + ((long)hh * 64 + c) * 2048 + m0 + wm;
        #pragma unroll
        for (int mi = 0; mi < 4; mi++) {
          union { u16 u[4]; float2 f; } pk;
          #pragma unroll
          for (int r = 0; r < 4; r++) pk.u[r] = f2bf(acc[mi][ni][r] + bn);
          *reinterpret_cast<float2*>(vrow + mi * 16 + quad * 4) = pk.f;
        }
      } else {
        float sc = (region == 0) ? 0.180336880f : 1.f;   // 0.125 * log2(e)
        #pragma unroll
        for (int mi = 0; mi < 4; mi++)
          #pragma unroll
          for (int r = 0; r < 4; r++) {
            int m = m0 + wm + mi * 16 + quad * 4 + r;
            D[(long)m * 1536 + n] = f2bf((acc[mi][ni][r] + bn) * sc);
          }
      }
    }
  } else {
    float* D = (float*)outp + bz * obst;
    const float* R = resid + bz * rbst;
    #pragma unroll
    for (int mi = 0; mi < 4; mi++)
      #pragma unroll
      for (int r = 0; r < 4; r++) {
        int m = m0 + wm + mi * 16 + quad * 4 + r;
        float bm = bias[m];
        #pragma unroll
        for (int ni = 0; ni < 4; ni++) {
          int n = n0 + wn + ni * 16 + l15;
          long idx = (long)m * N + n;
          D[idx] = acc[mi][ni][r] + bm + R[idx];
        }
      }
  }
}

// ---------- flash attention (S^T formulation, async dbuf K/V, no-max softmax) ----------
// qkv: (B,T,1536) bf16, Q pre-scaled by 0.125*log2e; vt: (B,NH,64,T) bf16.
// Scores s = (q.k)/8 are bounded (|s| << 127 in exp2 domain) -> softmax without
// max-subtraction: p = exp2(s*log2e), l = sum p (via ones-MFMA), no rescaling ever.
__global__ __launch_bounds__(256, 2) void attn(const u16* __restrict__ qkv,
                                               const u16* __restrict__ vt,
                                               u16* __restrict__ aout) {
  __shared__ __align__(16) u16 Ps[256 * 64];     // 32KB, P (wave-private rows, swizzled)
  __shared__ __align__(16) u16 Ks[2][64 * 64];   // 2x8KB
  __shared__ __align__(16) u16 Vs[2][64 * 64];   // 2x8KB
  const int tid = threadIdx.x, lane = tid & 63, wave = tid >> 6;
  const int l15 = lane & 15, quad = lane >> 4;
  const int sw = l15 & 7;                        // row-swizzle key
  const int b = blockIdx.y >> 3, h = blockIdx.y & 7;
  const int t0 = blockIdx.x * 256;
  const u16* qbase = qkv + (long)b * 2048 * 1536 + h * 192;
  const u16* vbase = vt + (long)(b * 8 + h) * 64 * 2048;

  // Q fragments straight from global (A-layout: 16B/lane)
  short8 qf[4][2];
  #pragma unroll
  for (int tqi = 0; tqi < 4; tqi++)
    #pragma unroll
    for (int ks = 0; ks < 2; ks++)
      qf[tqi][ks] = ld8(qbase + (long)(t0 + wave * 64 + tqi * 16 + l15) * 1536 + ks * 32 + quad * 8);

  // ones A-fragment for l-sum MFMA (bf16 1.0 = 0x3F80)
  short8 ones;
  #pragma unroll
  for (int j = 0; j < 8; j++) ones[j] = (short)0x3F80;

  // staging source pointers: lane covers phys chunk p, reads logical chunk c = (p&7)^(row&7)
  const u16* kg[2]; const u16* vg[2]; int ldso[2];
  #pragma unroll
  for (int half = 0; half < 2; half++) {
    int p = half * 256 + wave * 64 + lane;
    int row = p >> 3, c = (p & 7) ^ (row & 7);
    kg[half] = qbase + (long)row * 1536 + 64 + c * 8;
    vg[half] = vbase + (long)row * 2048 + c * 8;
    ldso[half] = (half * 256 + wave * 64) * 8;
  }
  #pragma unroll
  for (int half = 0; half < 2; half++) {
    async_ld16(kg[half], &Ks[0][ldso[half]]);
    async_ld16(vg[half], &Vs[0][ldso[half]]);
  }

  floatx4 accO[4][4];   // [ci][tqi]: row=c, col=tq
  floatx4 lacc[4];      // [tqi]: all regs hold sum_k P (ones-MFMA)
  #pragma unroll
  for (int ci = 0; ci < 4; ci++)
    #pragma unroll
    for (int tqi = 0; tqi < 4; tqi++) accO[ci][tqi] = (floatx4){0.f, 0.f, 0.f, 0.f};
  #pragma unroll
  for (int tqi = 0; tqi < 4; tqi++) lacc[tqi] = (floatx4){0.f, 0.f, 0.f, 0.f};

  for (int it = 0; it < 32; it++) {
    const u16* kb = Ks[it & 1];
    const u16* vb = Vs[it & 1];
    __syncthreads();                     // publishes tile it; frees buffer it^1
    if (it < 31) {                       // prefetch tile it+1 (drained at next barrier)
      int s1 = (it + 1) * 64;
      u16* kn = Ks[(it & 1) ^ 1];
      u16* vn = Vs[(it & 1) ^ 1];
      #pragma unroll
      for (int half = 0; half < 2; half++) {
        async_ld16(kg[half] + (long)s1 * 1536, &kn[ldso[half]]);
        async_ld16(vg[half] + s1,              &vn[ldso[half]]);
      }
    }

    // S^T[tk][tq] = sum_c K[tk][c] * Q[tq][c]
    floatx4 sacc[4][4];   // [tki][tqi]
    #pragma unroll
    for (int i = 0; i < 4; i++)
      #pragma unroll
      for (int j = 0; j < 4; j++) sacc[i][j] = (floatx4){0.f, 0.f, 0.f, 0.f};
    #pragma unroll
    for (int ks = 0; ks < 2; ks++) {
      short8 kf[4];
      #pragma unroll
      for (int tki = 0; tki < 4; tki++)
        kf[tki] = ld8(&kb[((tki * 16 + l15) << 6) + (((ks * 4 + quad) ^ sw) << 3)]);
      #pragma unroll
      for (int tki = 0; tki < 4; tki++)
        #pragma unroll
        for (int tqi = 0; tqi < 4; tqi++)
          sacc[tki][tqi] = __builtin_amdgcn_mfma_f32_16x16x32_bf16(kf[tki], qf[tqi][ks], sacc[tki][tqi], 0, 0, 0);
    }

    // p = exp2(s) (no max-sub; bounded domain), pack & write P
    #pragma unroll
    for (int tqi = 0; tqi < 4; tqi++) {
      int prow = (wave * 64 + tqi * 16 + l15) << 6;
      #pragma unroll
      for (int tki = 0; tki < 4; tki++) {
        float p0 = __builtin_amdgcn_exp2f(sacc[tki][tqi][0]);
        float p1 = __builtin_amdgcn_exp2f(sacc[tki][tqi][1]);
        float p2 = __builtin_amdgcn_exp2f(sacc[tki][tqi][2]);
        float p3 = __builtin_amdgcn_exp2f(sacc[tki][tqi][3]);
        union { u32 u[2]; float2 f; } pk;
        pk.u[0] = __builtin_amdgcn_perm(__float_as_uint(p1), __float_as_uint(p0), 0x07060302);
        pk.u[1] = __builtin_amdgcn_perm(__float_as_uint(p3), __float_as_uint(p2), 0x07060302);
        int c16 = tki * 2 + (quad >> 1);
        *reinterpret_cast<float2*>(
            &Ps[prow + ((c16 ^ sw) << 3) + ((quad & 1) << 2)]) = pk.f;
      }
    }

    // O^T[c][tq] += sum_tk V^T[c][tk] * P[tq][tk]; l[tq] += sum_tk P (ones row)
    #pragma unroll
    for (int ks = 0; ks < 2; ks++) {
      short8 vf[4], pf[4];
      #pragma unroll
      for (int ci = 0; ci < 4; ci++)
        vf[ci] = ld8(&vb[((ci * 16 + l15) << 6) + (((ks * 4 + quad) ^ sw) << 3)]);
      #pragma unroll
      for (int tqi = 0; tqi < 4; tqi++)
        pf[tqi] = ld8(&Ps[((wave * 64 + tqi * 16 + l15) << 6) + (((ks * 4 + quad) ^ sw) << 3)]);
      #pragma unroll
      for (int tqi = 0; tqi < 4; tqi++)
        lacc[tqi] = __builtin_amdgcn_mfma_f32_16x16x32_bf16(ones, pf[tqi], lacc[tqi], 0, 0, 0);
      #pragma unroll
      for (int ci = 0; ci < 4; ci++)
        #pragma unroll
        for (int tqi = 0; tqi < 4; tqi++)
          accO[ci][tqi] = __builtin_amdgcn_mfma_f32_16x16x32_bf16(vf[ci], pf[tqi], accO[ci][tqi], 0, 0, 0);
    }
  }

  // epilogue: normalize, write a (B,T,C) bf16; lane holds 4 consecutive c
  u16* ob = aout + ((long)b * 2048 + t0 + wave * 64) * 512 + h * 64;
  #pragma unroll
  for (int tqi = 0; tqi < 4; tqi++) {
    float invl = 1.f / lacc[tqi][0];
    #pragma unroll
    for (int ci = 0; ci < 4; ci++) {
      union { u16 u[4]; float2 f; } pk;
      #pragma unroll
      for (int r = 0; r < 4; r++) pk.u[r] = f2bf(accO[ci][tqi][r] * invl);
      *reinterpret_cast<float2*>(ob + (long)(tqi * 16 + l15) * 512 + ci * 16 + quad * 4) = pk.f;
    }
  }
}

// ---------- launch ----------
extern "C" void kernel_launch(void* const* d_in, const int* in_sizes, int n_in,
                              void* d_out, int out_size, void* d_ws, size_t ws_size,
                              hipStream_t stream) {
  const float* x   = (const float*)d_in[0];
  const float* g1  = (const float*)d_in[1];
  const float* be1 = (const float*)d_in[2];
  const float* wq  = (const float*)d_in[3];
  const float* bq  = (const float*)d_in[4];
  const float* g2  = (const float*)d_in[5];
  const float* be2 = (const float*)d_in[6];
  const float* wp  = (const float*)d_in[7];
  const float* bp  = (const float*)d_in[8];

  char* ws = (char*)d_ws;
  u16*   xn   = (u16*)ws;                        // 16.8 MB, dead after gemm1
  u16*   a    = (u16*)ws;                        // bf16 attn out, alias xn (disjoint lifetime)
  u16*   qkvb = (u16*)(ws + 33554432);           // 50.3 MB (q/k live, v-holes unused)
  u16*   hn   = (u16*)(ws + 83886080);           // 16.8 MB, gn2 -> gemm2
  u16*   vtb  = hn;                              // alias: Vt lifetime gemm1 -> attn
  u16*   wqb  = (u16*)(ws + 100663296);          // 1.6 MB
  u16*   wpb  = (u16*)(ws + 102236160);          // 0.5 MB

  cast_both<<<1024, 256, 0, stream>>>(wq, wqb, wp, wpb);
  gn_ct<<<256, 1024, 0, stream>>>(x, g1, be1, xn);
  // qkv[b][t][o] = sum_c xn[b][t][c] * Wq[o][c] + bq[o]  (+ q-scale, v->Vt)
  gemm_tn<1><<<dim3(12, 16, 8), 256, 0, stream>>>(
      xn, (long)2048 * 512, wqb, 0, bq, nullptr, 0, qkvb, (long)2048 * 1536, vtb, 512);
  attn<<<dim3(8, 64), 256, 0, stream>>>(qkvb, vtb, a);
  gn_tc<<<256, 1024, 0, stream>>>(a, g2, be2, hn);
  // out[b][o][t] = x[b][o][t] + bp[o] + sum_c Wp[o][c] * hn[b][t][c]
  gemm_tn<0><<<dim3(16, 4, 8), 256, 0, stream>>>(
      wpb, 0, hn, (long)2048 * 512, bp, x, (long)512 * 2048, d_out, (long)512 * 2048, nullptr, 512);
}